// Round 11
// baseline (796.942 us; speedup 1.0000x reference)
//
#include <hip/hip_runtime.h>

#define LBL 64
#define TT 1024
#define BB 256
#define BOS 62
#define EOS 63
#define NEGV -10000.0f
#define WPB 8   // sentences (waves) per forward block -> 2 waves/SIMD

typedef float v4f __attribute__((ext_vector_type(4)));

__device__ __forceinline__ float rl_f(float v, int l) {
    return __uint_as_float(__builtin_amdgcn_readlane(__float_as_uint(v), l));
}

// ---------------- forward: 8 independent sentences per block ----------------
// wave wv owns sentence b = blk*8+wv. No inter-wave sync in the loop; two
// waves share each SIMD so per-wave stalls (LDS latency, dep bubbles) overlap.
// bp bytes packed 4 steps/u32 -> global d_ws (fire-and-forget coalesced).
__global__ __launch_bounds__(512, 2) void viterbi_fwd(
    const float* __restrict__ X, const float* __restrict__ trans,
    float* __restrict__ out, unsigned* __restrict__ bpG, int* __restrict__ tags)
{
    __shared__ __align__(16) float tlds[LBL * LBL];   // [p][n], 16 KiB, read-only
    __shared__ __align__(16) float fvrow[WPB][LBL];   // per-wave fv_{t-1}

    const int tid  = threadIdx.x;
    const int lane = tid & 63;                 // next-label n
    const int wv   = __builtin_amdgcn_readfirstlane(tid >> 6);
    const int b    = blockIdx.x * WPB + wv;

    float tc[LBL];
#pragma unroll
    for (int p = 0; p < LBL; ++p) tc[p] = trans[p * LBL + lane];
    // cooperative tlds init (wave wv writes rows p%8==wv), then one barrier
#pragma unroll
    for (int p = 0; p < 8; ++p)
        tlds[(p * 8 + wv) * LBL + lane] = tc[p * 8 + wv];

    float fvv = (lane == BOS) ? 0.0f : NEGV;
    fvrow[wv][lane] = fvv;
    __syncthreads();                           // once, outside the loop

    const float* Xb  = X + (size_t)b * TT * LBL + lane;
    unsigned*    bpW = bpG + (size_t)b * (TT / 4) * LBL + lane;

    auto STEP = [&](float e) -> unsigned {
        // value phase: m = max_p(fv[p]+T[p][n]); fv via readlane (registers)
        float vg[8];
#pragma unroll
        for (int g = 0; g < 8; ++g) {
            float s0 = rl_f(fvv, 8*g+0) + tc[8*g+0];
            float s1 = rl_f(fvv, 8*g+1) + tc[8*g+1];
            float s2 = rl_f(fvv, 8*g+2) + tc[8*g+2];
            float s3 = rl_f(fvv, 8*g+3) + tc[8*g+3];
            float s4 = rl_f(fvv, 8*g+4) + tc[8*g+4];
            float s5 = rl_f(fvv, 8*g+5) + tc[8*g+5];
            float s6 = rl_f(fvv, 8*g+6) + tc[8*g+6];
            float s7 = rl_f(fvv, 8*g+7) + tc[8*g+7];
            vg[g] = fmaxf(fmaxf(fmaxf(s0, s1), fmaxf(s2, s3)),
                          fmaxf(fmaxf(s4, s5), fmaxf(s6, s7)));
        }
        const float m = fmaxf(fmaxf(fmaxf(vg[0], vg[1]), fmaxf(vg[2], vg[3])),
                              fmaxf(fmaxf(vg[4], vg[5]), fmaxf(vg[6], vg[7])));

        // index phase (feeds bp only): first group == m, recompute 8 sums
        // (bitwise-identical f32 adds), first element == m  => np.argmax
        int gs = 7;
#pragma unroll
        for (int g = 6; g >= 0; --g) gs = (vg[g] == m) ? g : gs;

        const v4f fq0 = *(const v4f*)&fvrow[wv][(gs << 3)];
        const v4f fq1 = *(const v4f*)&fvrow[wv][(gs << 3) + 4];
        const float* tg = (const float*)((const char*)tlds + (gs << 11)) + lane;
        float q0 = fq0.x + tg[0 * LBL];
        float q1 = fq0.y + tg[1 * LBL];
        float q2 = fq0.z + tg[2 * LBL];
        float q3 = fq0.w + tg[3 * LBL];
        float q4 = fq1.x + tg[4 * LBL];
        float q5 = fq1.y + tg[5 * LBL];
        float q6 = fq1.z + tg[6 * LBL];
        float q7 = fq1.w + tg[7 * LBL];
        int k = 7;
        k = (q6 == m) ? 6 : k;
        k = (q5 == m) ? 5 : k;
        k = (q4 == m) ? 4 : k;
        k = (q3 == m) ? 3 : k;
        k = (q2 == m) ? 2 : k;
        k = (q1 == m) ? 1 : k;
        k = (q0 == m) ? 0 : k;

        fvv = m + e;                 // exact f32 add == numpy
        fvrow[wv][lane] = fvv;       // after the gather reads (program order)
        return (unsigned)((gs << 3) | k);
    };

    float eC[8], eN[8];
#pragma unroll
    for (int j = 0; j < 8; ++j) eC[j] = Xb[(size_t)j * LBL];

    for (int base = 0; base < TT; base += 8) {
        if (base + 8 < TT) {                   // peeled guard (uniform branch)
#pragma unroll
            for (int j = 0; j < 8; ++j)
                eN[j] = Xb[(size_t)(base + 8 + j) * LBL];
        }
        unsigned b0 = STEP(eC[0]);
        unsigned b1 = STEP(eC[1]);
        unsigned b2 = STEP(eC[2]);
        unsigned b3 = STEP(eC[3]);
        bpW[(size_t)(base >> 2) * LBL] = b0 | (b1 << 8) | (b2 << 16) | (b3 << 24);
        b0 = STEP(eC[4]);
        b1 = STEP(eC[5]);
        b2 = STEP(eC[6]);
        b3 = STEP(eC[7]);
        bpW[(size_t)((base >> 2) + 1) * LBL] = b0 | (b1 << 8) | (b2 << 16) | (b3 << 24);
#pragma unroll
        for (int j = 0; j < 8; ++j) eC[j] = eN[j];
    }

    // termination + wave argmax (butterfly, lower index wins ties)
    float bv = fvv + trans[lane * LBL + EOS];
    int   bi = lane;
#pragma unroll
    for (int d = 1; d < 64; d <<= 1) {
        float ov = __shfl_xor(bv, d, 64);
        int   oi = __shfl_xor(bi, d, 64);
        if (ov > bv || (ov == bv && oi < bi)) { bv = ov; bi = oi; }
    }
    if (lane == 0) { out[b] = bv; tags[b] = bi; }
}

// ---------------- backtrack: one wave per sentence ----------------
// t-indexed word loads (tag-INDEPENDENT -> deep prefetch), register-speed
// readlane chase; path staged in 1 KiB LDS then written coalesced.
__global__ __launch_bounds__(64, 1) void viterbi_bt(
    const unsigned* __restrict__ bpG, const int* __restrict__ tags,
    float* __restrict__ out)
{
    __shared__ unsigned char path_s[TT];
    const int lane = threadIdx.x;
    const int b    = blockIdx.x;
    const unsigned* bpW = bpG + (size_t)b * (TT / 4) * LBL + lane;

    int stag = tags[b];                        // wave-uniform start tag

    unsigned w0 = bpW[255 * LBL];
    unsigned w1 = bpW[254 * LBL];
    unsigned w2 = bpW[253 * LBL];
    unsigned w3 = bpW[252 * LBL];

    auto CHASE = [&](unsigned w, int t4) {
#pragma unroll
        for (int sub = 3; sub >= 0; --sub) {
            const int t = 4 * t4 + sub;
            if (lane == (t & 63)) path_s[t] = (unsigned char)stag;
            unsigned wr = (unsigned)__builtin_amdgcn_readlane((int)w, stag);
            stag = (int)((wr >> (8 * sub)) & 0xFFu);
        }
    };

    for (int t4 = 255; t4 >= 3; t4 -= 4) {
        int p0 = t4 - 4, p1 = t4 - 5, p2 = t4 - 6, p3 = t4 - 7;
        if (p0 < 0) p0 = 0;  if (p1 < 0) p1 = 0;
        if (p2 < 0) p2 = 0;  if (p3 < 0) p3 = 0;
        unsigned n0 = bpW[(size_t)p0 * LBL];
        unsigned n1 = bpW[(size_t)p1 * LBL];
        unsigned n2 = bpW[(size_t)p2 * LBL];
        unsigned n3 = bpW[(size_t)p3 * LBL];
        CHASE(w0, t4);
        CHASE(w1, t4 - 1);
        CHASE(w2, t4 - 2);
        CHASE(w3, t4 - 3);
        w0 = n0; w1 = n1; w2 = n2; w3 = n3;
    }

    // coalesced float path write (single wave; LDS program order)
    float* po = out + BB + (size_t)b * TT;
#pragma unroll
    for (int i = 0; i < TT / LBL; ++i)
        po[i * LBL + lane] = (float)path_s[i * LBL + lane];
}

extern "C" void kernel_launch(void* const* d_in, const int* in_sizes, int n_in,
                              void* d_out, int out_size, void* d_ws, size_t ws_size,
                              hipStream_t stream)
{
    const float* X     = (const float*)d_in[0];   // [256, 1024, 64]
    const float* trans = (const float*)d_in[1];   // [64, 64]
    float* out = (float*)d_out;                   // [256] scores ++ [256*1024] path

    // ws layout: bp words [256][256][64] u32 = 16 MiB, then tags [256] int
    unsigned* bpG  = (unsigned*)d_ws;
    int*      tags = (int*)((char*)d_ws + (size_t)BB * (TT / 4) * LBL * 4);

    viterbi_fwd<<<dim3(BB / WPB), dim3(512), 0, stream>>>(X, trans, out, bpG, tags);
    viterbi_bt <<<dim3(BB),       dim3(64),  0, stream>>>(bpG, tags, out);
}

// Round 12
// 575.857 us; speedup vs baseline: 1.3839x; 1.3839x over previous
//
#include <hip/hip_runtime.h>

#define LBL 64
#define TT 1024
#define BB 256
#define BOS 62
#define EOS 63
#define NEGV -10000.0f

typedef float v2f __attribute__((ext_vector_type(2)));
typedef float v4f __attribute__((ext_vector_type(4)));

// ONE WAVE per sentence, zero barriers. lane = next-label n.
// Value phase: fv broadcast via LDS (1 ds_write + 16 broadcast ds_read_b128),
// packed pk_add/pk_max, group maxima -> m.  INDEX PHASE IS DEFERRED ONE STEP:
// its dependent LDS gather issues at the top of step t+1 and its latency hides
// under that step's value phase (index feeds only bp, never fv).
// fvrow is double-buffered; same-wave DS FIFO order makes it race-free
// (validated r9/r10, absmax=0).
__global__ __launch_bounds__(64, 1) void viterbi_kernel(
    const float* __restrict__ X, const float* __restrict__ trans,
    float* __restrict__ out)
{
    __shared__ __align__(16) float fvrow[2][LBL];    // fv double buffer
    __shared__ __align__(16) float tlds[LBL * LBL];  // [p][n] layout, 16 KiB
    __shared__ unsigned char bp[TT][LBL];            // 64 KiB backpointers
    __shared__ unsigned char path_s[TT];

    const int lane = threadIdx.x;            // next-label n
    const int b    = blockIdx.x;

    // tc2[i] = {T[2i][n], T[2i+1][n]} packed in register pairs (64 VGPR)
    v2f tc2[32];
#pragma unroll
    for (int i = 0; i < 32; ++i) {
        tc2[i][0] = trans[(2*i)   * LBL + lane];
        tc2[i][1] = trans[(2*i+1) * LBL + lane];
    }
    // LDS copy in [p][n] layout: deferred gather reads are lane-consecutive
    // (conflict-free, r10-verified: SQ_LDS_BANK_CONFLICT == 0)
#pragma unroll
    for (int i = 0; i < 32; ++i) {
        tlds[(2*i)   * LBL + lane] = tc2[i][0];
        tlds[(2*i+1) * LBL + lane] = tc2[i][1];
    }

    const float* Xb = X + (size_t)b * TT * LBL + lane;

    float fvv = (lane == BOS) ? 0.0f : NEGV;   // fv_{-1}
    fvrow[0][lane] = fvv;                      // step 0 reads buffer 0

    float dm = 0.0f; int dgs = 0;              // deferred index state (t-1)

    auto STEP = [&](int t, float e, bool dodef) {
        const int par = t & 1;

        // ---- deferred index completion for step t-1 (reads fvrow[par^1],
        //      which still holds fv_{t-2}; overwritten only at the END of
        //      this step — same-wave DS FIFO keeps reads ahead of the write)
        if (dodef) {
            const float* fp = &fvrow[par ^ 1][dgs << 3];
            const v4f fa = *(const v4f*)fp;          // broadcast b128
            const v4f fb = *(const v4f*)(fp + 4);
            const float* tg = &tlds[(dgs << 3) * LBL + lane];
            float q0 = fa.x + tg[0 * LBL];           // same f32 adds as value
            float q1 = fa.y + tg[1 * LBL];           //  phase -> bitwise equal
            float q2 = fa.z + tg[2 * LBL];
            float q3 = fa.w + tg[3 * LBL];
            float q4 = fb.x + tg[4 * LBL];
            float q5 = fb.y + tg[5 * LBL];
            float q6 = fb.z + tg[6 * LBL];
            float q7 = fb.w + tg[7 * LBL];
            int k = 7;
            k = (q6 == dm) ? 6 : k;
            k = (q5 == dm) ? 5 : k;
            k = (q4 == dm) ? 4 : k;
            k = (q3 == dm) ? 3 : k;
            k = (q2 == dm) ? 2 : k;
            k = (q1 == dm) ? 1 : k;
            k = (q0 == dm) ? 0 : k;                  // lowest k = first occ.
            bp[t - 1][lane] = (unsigned char)((dgs << 3) | k);
        }

        // ---- value phase: m = max_p(fv_{t-1}[p] + T[p][n]) ----
        const v4f* fr = (const v4f*)fvrow[par];
        float vgs[8];
#pragma unroll
        for (int g = 0; g < 8; ++g) {
            const v4f fa = fr[2*g];                  // broadcast b128 reads
            const v4f fb = fr[2*g + 1];
            v2f s0 = __builtin_shufflevector(fa, fa, 0, 1) + tc2[4*g+0];
            v2f s1 = __builtin_shufflevector(fa, fa, 2, 3) + tc2[4*g+1];
            v2f s2 = __builtin_shufflevector(fb, fb, 0, 1) + tc2[4*g+2];
            v2f s3 = __builtin_shufflevector(fb, fb, 2, 3) + tc2[4*g+3];
            v2f w0 = __builtin_elementwise_max(s0, s1);   // v_pk_max_f32
            v2f w1 = __builtin_elementwise_max(s2, s3);
            v2f w  = __builtin_elementwise_max(w0, w1);
            vgs[g] = fmaxf(w[0], w[1]);              // exact group max
        }
        const float m =
            fmaxf(fmaxf(fmaxf(vgs[0], vgs[1]), fmaxf(vgs[2], vgs[3])),
                  fmaxf(fmaxf(vgs[4], vgs[5]), fmaxf(vgs[6], vgs[7])));

        // first group containing m (ascending cndmask chain = first occ.)
        int gs = 7;
#pragma unroll
        for (int g = 6; g >= 0; --g) gs = (vgs[g] == m) ? g : gs;

        dm = m; dgs = gs;                 // hand to next step's deferred phase
        fvv = m + e;                      // exact f32 add == numpy
        fvrow[par ^ 1][lane] = fvv;       // publish fv_t (after all reads)
    };

    // emission double-window prefetch (no barriers -> loads never drained)
    float eC[8], eN[8];
#pragma unroll
    for (int j = 0; j < 8; ++j) eC[j] = Xb[(size_t)j * LBL];

    // peeled first window (t=0 has no deferred work)
#pragma unroll
    for (int j = 0; j < 8; ++j) eN[j] = Xb[(size_t)(8 + j) * LBL];
    STEP(0, eC[0], false);
#pragma unroll
    for (int j = 1; j < 8; ++j) STEP(j, eC[j], true);
#pragma unroll
    for (int j = 0; j < 8; ++j) eC[j] = eN[j];

    for (int base = 8; base < TT; base += 8) {
        if (base + 8 < TT) {                   // uniform scalar branch
#pragma unroll
            for (int j = 0; j < 8; ++j)
                eN[j] = Xb[(size_t)(base + 8 + j) * LBL];
        }
#pragma unroll
        for (int j = 0; j < 8; ++j) STEP(base + j, eC[j], true);
#pragma unroll
        for (int j = 0; j < 8; ++j) eC[j] = eN[j];
    }

    // epilogue: deferred index for t = TT-1 (fvrow[1] still holds fv_{TT-2})
    {
        const float* fp = &fvrow[1][dgs << 3];
        const v4f fa = *(const v4f*)fp;
        const v4f fb = *(const v4f*)(fp + 4);
        const float* tg = &tlds[(dgs << 3) * LBL + lane];
        float q0 = fa.x + tg[0 * LBL];
        float q1 = fa.y + tg[1 * LBL];
        float q2 = fa.z + tg[2 * LBL];
        float q3 = fa.w + tg[3 * LBL];
        float q4 = fb.x + tg[4 * LBL];
        float q5 = fb.y + tg[5 * LBL];
        float q6 = fb.z + tg[6 * LBL];
        float q7 = fb.w + tg[7 * LBL];
        int k = 7;
        k = (q6 == dm) ? 6 : k;
        k = (q5 == dm) ? 5 : k;
        k = (q4 == dm) ? 4 : k;
        k = (q3 == dm) ? 3 : k;
        k = (q2 == dm) ? 2 : k;
        k = (q1 == dm) ? 1 : k;
        k = (q0 == dm) ? 0 : k;
        bp[TT - 1][lane] = (unsigned char)((dgs << 3) | k);
    }

    // ---- termination + wave argmax (butterfly, lower index wins ties) ----
    float bv = fvv + trans[lane * LBL + EOS];
    int   bi = lane;
#pragma unroll
    for (int d = 1; d < 64; d <<= 1) {
        float ov = __shfl_xor(bv, d, 64);
        int   oi = __shfl_xor(bi, d, 64);
        if (ov > bv || (ov == bv && oi < bi)) { bv = ov; bi = oi; }
    }
    if (lane == 0) out[b] = bv;

    // ---- backtrack: prefetch bp rows, chase via readlane (r5-validated) ----
    int stag = bi;   // wave-uniform
    unsigned char r0 = bp[TT-1][lane];
    unsigned char r1 = bp[TT-2][lane];
    unsigned char r2 = bp[TT-3][lane];
    unsigned char r3 = bp[TT-4][lane];
    for (int t4 = TT - 1; t4 >= 3; t4 -= 4) {
        int q0 = t4-4, q1 = t4-5, q2 = t4-6, q3 = t4-7;
        if (q0 < 0) q0 = 0;  if (q1 < 0) q1 = 0;
        if (q2 < 0) q2 = 0;  if (q3 < 0) q3 = 0;
        unsigned char m0 = bp[q0][lane];
        unsigned char m1 = bp[q1][lane];
        unsigned char m2 = bp[q2][lane];
        unsigned char m3 = bp[q3][lane];
        if (lane == ((t4-0) & 63)) path_s[t4-0] = (unsigned char)stag;
        stag = __builtin_amdgcn_readlane((int)r0, stag);
        if (lane == ((t4-1) & 63)) path_s[t4-1] = (unsigned char)stag;
        stag = __builtin_amdgcn_readlane((int)r1, stag);
        if (lane == ((t4-2) & 63)) path_s[t4-2] = (unsigned char)stag;
        stag = __builtin_amdgcn_readlane((int)r2, stag);
        if (lane == ((t4-3) & 63)) path_s[t4-3] = (unsigned char)stag;
        stag = __builtin_amdgcn_readlane((int)r3, stag);
        r0 = m0; r1 = m1; r2 = m2; r3 = m3;
    }

    // coalesced float path write (single wave, LDS program order)
    float* po = out + BB + (size_t)b * TT;
#pragma unroll
    for (int i = 0; i < TT / LBL; ++i)
        po[i * LBL + lane] = (float)path_s[i * LBL + lane];
}

extern "C" void kernel_launch(void* const* d_in, const int* in_sizes, int n_in,
                              void* d_out, int out_size, void* d_ws, size_t ws_size,
                              hipStream_t stream)
{
    const float* X     = (const float*)d_in[0];   // [256, 1024, 64]
    const float* trans = (const float*)d_in[1];   // [64, 64]
    float* out = (float*)d_out;                   // [256] scores ++ [256*1024] path

    viterbi_kernel<<<dim3(BB), dim3(64), 0, stream>>>(X, trans, out);
}